// Round 5
// baseline (620.331 us; speedup 1.0000x reference)
//
#include <hip/hip_runtime.h>

#define S_LEN 2048
#define B_SZ 2048

typedef float v2 __attribute__((ext_vector_type(2)));
#define FMA2(a, b, c) __builtin_elementwise_fma((a), (b), (c))

// Pure-VALU DPP move (quad_perm patterns; old=0, bound_ctrl=1).
template <int CTRL>
__device__ __forceinline__ float dppmov(float v) {
  int r = __builtin_amdgcn_update_dpp(0, __builtin_bit_cast(int, v), CTRL, 0xF,
                                      0xF, true);
  return __builtin_bit_cast(float, r);
}

// DPP with explicit old operand: invalid lanes (bound_ctrl=0) keep `old`.
// row_shr:4 invalid lanes are exactly the l==0 lanes -> x rides in `old`.
template <int CTRL, bool BC>
__device__ __forceinline__ float dppold(float old, float v) {
  int r = __builtin_amdgcn_update_dpp(__builtin_bit_cast(int, old),
                                      __builtin_bit_cast(int, v), CTRL, 0xF,
                                      0xF, BC);
  return __builtin_bit_cast(float, r);
}

// R14 (resubmit; R4's bench died on GPU acquisition, no data).
// R10-R13 triangulated: time/tick = 2.8cy x Ninstr + ~210cy of UNHIDDEN
// chain latency (exp->rcp->fma->exp->rcp) -- a single wave per SIMD
// (512 waves / 1024 SIMDs) issues in-order and nothing fills its stalls.
// Fix: 1 batch per wave (rows b=1..3 duplicate row 0's batch; identical
// instruction stream) -> 2048 blocks -> 8 blocks/CU -> 2 waves/SIMD.
// The co-resident wave's instructions retire during this wave's chain
// stalls: predicted time/tick ~= max(2 x issue, chain) ~= 230cy vs 368.
// v_rcp restored (R13's Newton rcp was latency-neutral, issue-costly).
// Handoff DPPs moved to macro end writing hx directly (saves the ns->hx
// moves; warm-up-exact: for every kept tick tau>=2l, layer l-1 was not
// reset at tau-1, so pre/post-RESET hv coincide).
#define TICK(U)                                                                \
  {                                                                            \
    v2 h01, h23;                                                               \
    h01.x = hx0;                                                               \
    h01.y = hx1;                                                               \
    h23.x = hx2;                                                               \
    h23.y = hx3;                                                               \
    v2 A0 = FMA2(wi01[0], h01, bias2[0]);                                      \
    v2 A1 = FMA2(wi01[1], h01, bias2[1]);                                      \
    v2 A2 = FMA2(wi01[2], h01, bias2[2]);                                      \
    v2 A3 = FMA2(wi01[3], h01, bias2[3]);                                      \
    A0 = FMA2(wi23[0], h23, A0);                                               \
    A1 = FMA2(wi23[1], h23, A1);                                               \
    A2 = FMA2(wi23[2], h23, A2);                                               \
    A3 = FMA2(wi23[3], h23, A3);                                               \
    A0 = FMA2(wh01[0], hv01, A0);                                              \
    A1 = FMA2(wh01[1], hv01, A1);                                              \
    A2 = FMA2(wh01[2], hv01, A2);                                              \
    A3 = FMA2(wh01[3], hv01, A3);                                              \
    A0 = FMA2(wh23[0], hv23, A0);                                              \
    A1 = FMA2(wh23[1], hv23, A1);                                              \
    A2 = FMA2(wh23[2], hv23, A2);                                              \
    A3 = FMA2(wh23[3], hv23, A3);                                              \
    float a0 = A0.x + A0.y, a1 = A1.x + A1.y;                                  \
    float a2 = A2.x + A2.y, a3 = A3.x + A3.y;                                  \
    float e0 = __builtin_amdgcn_exp2f(a0); /* gates pre-scaled by kk_t */      \
    float e1 = __builtin_amdgcn_exp2f(a1);                                     \
    float e2 = __builtin_amdgcn_exp2f(a2);                                     \
    float e3 = __builtin_amdgcn_exp2f(a3);                                     \
    float r0 = __builtin_amdgcn_rcpf(1.0f + e0); /* sigmoid(i) */              \
    float r1 = __builtin_amdgcn_rcpf(1.0f + e1); /* sigmoid(f) */              \
    float r2 = __builtin_amdgcn_rcpf(1.0f + e2); /* (tanh(g)+1)/2 */           \
    float r3 = __builtin_amdgcn_rcpf(1.0f + e3); /* sigmoid(o) */              \
    float gi = KT * r0;               /* KT fold: cKT = KT*c */                \
    float gg = fmaf(2.0f, r2, -1.0f); /* tanh(g) */                            \
    cKT = fmaf(r1, cKT, gi * gg);                                              \
    float te = __builtin_amdgcn_exp2f(cKT);                                    \
    float tr = __builtin_amdgcn_rcpf(1.0f + te);                               \
    float go2 = r3 + r3;                                                       \
    float hh = fmaf(go2, tr, -r3); /* = o * tanh(c) */                         \
    /* next-tick input from OLD hv (pre-update); l0 lanes keep xc (old) */     \
    hx0 = dppold<0x114, false>(xc##U.x, hv01.x); /* row_shr:4 */               \
    hx1 = dppold<0x114, false>(xc##U.y, hv01.y);                               \
    hx2 = dppold<0x114, true>(0.0f, hv23.x);                                   \
    hx3 = dppold<0x114, true>(0.0f, hv23.y);                                   \
    hv01.x = hh;                                                               \
    hv01.y = dppmov<0x39>(hh); /* h_{(j+1)&3} */                               \
    hv23.x = dppmov<0x4E>(hh); /* h_{(j+2)&3} */                               \
    hv23.y = dppmov<0x93>(hh); /* h_{(j+3)&3} */                               \
    /* y slot: partial dot (horizontal add deferred to epoch store) */         \
    y##U = FMA2(wo01v, hv01, bo2);                                             \
    y##U = FMA2(wo23v, hv23, y##U);                                            \
  }

// warm-up reset: layer l is live from tau = 2l
#define RESET(U)                                                               \
  if (2 * l > (U)) {                                                           \
    cKT = 0.0f;                                                                \
    hv01.x = 0.0f;                                                             \
    hv01.y = 0.0f;                                                             \
    hv23.x = 0.0f;                                                             \
    hv23.y = 0.0f;                                                             \
  }

// reload slot U (just consumed) with its value for the NEXT epoch:
// epoch k's pointer pxk = px + (8k+9)*B_SZ + bidx -> slot U := x(8k+9+U)
#define XLOAD(U) xc##U = pxk[(U)*B_SZ];
#define XLOAD7C xc7 = pxk[6 * B_SZ]; /* tail clamp: x(2047) dup */

#define YST(U) ypk[(U)*B_SZ] = y##U.x + y##U.y;

__global__ void __launch_bounds__(64, 2)
    lstm_kernel(const float *__restrict__ x, const float *__restrict__ Wih0,
                const float *__restrict__ Whh0, const float *__restrict__ bih0,
                const float *__restrict__ bhh0, const float *__restrict__ Wihr,
                const float *__restrict__ Whhr, const float *__restrict__ bihr,
                const float *__restrict__ bhhr, const float *__restrict__ Wout,
                const float *__restrict__ bout, float *__restrict__ out) {
  const int lane = threadIdx.x & 63;
  const int l = (lane >> 2) & 3; // layer
  const int j = lane & 3;        // hidden unit
  // ONE batch per wave: rows b=0..3 all process batch blockIdx.x
  // (duplicate work; buys 2 waves/SIMD of latency hiding).
  const int bidx = blockIdx.x;
  const bool lz = (l == 0);
  const bool yl = (lane == 12); // single writer: b=0, l=3, j=0

  const float L2E = 1.4426950408889634f;
  const float KT = -2.8853900817779268f; // -2*log2(e)
  const float kks[4] = {-L2E, -L2E, -2.0f * L2E, -L2E};

  // ---- per-lane weights: all 4 gates of hidden j, layer l; pk-paired,
  //      pre-scaled by kk_t; wh AND (l>0) wi pre-rotated by j to match
  //      the rotated h convention of the row_shr:4 handoff. ----
  v2 wi01[4], wi23[4], wh01[4], wh23[4], bias2[4];
#pragma unroll
  for (int t = 0; t < 4; ++t) {
    const int row = t * 4 + j;
    const float kk = kks[t];
    float i0, i1, i2, i3, w0, w1, w2, w3, bs;
    if (l == 0) {
      i0 = Wih0[row * 2 + 0];
      i1 = Wih0[row * 2 + 1];
      i2 = 0.0f;
      i3 = 0.0f;
      w0 = Whh0[row * 4 + j];
      w1 = Whh0[row * 4 + ((j + 1) & 3)];
      w2 = Whh0[row * 4 + ((j + 2) & 3)];
      w3 = Whh0[row * 4 + ((j + 3) & 3)];
      bs = bih0[row] + bhh0[row];
    } else {
      const int m = l - 1;
      i0 = Wihr[m * 64 + row * 4 + j];
      i1 = Wihr[m * 64 + row * 4 + ((j + 1) & 3)];
      i2 = Wihr[m * 64 + row * 4 + ((j + 2) & 3)];
      i3 = Wihr[m * 64 + row * 4 + ((j + 3) & 3)];
      w0 = Whhr[m * 64 + row * 4 + j];
      w1 = Whhr[m * 64 + row * 4 + ((j + 1) & 3)];
      w2 = Whhr[m * 64 + row * 4 + ((j + 2) & 3)];
      w3 = Whhr[m * 64 + row * 4 + ((j + 3) & 3)];
      bs = bihr[m * 16 + row] + bhhr[m * 16 + row];
    }
    wi01[t].x = kk * i0;
    wi01[t].y = kk * i1;
    wi23[t].x = kk * i2;
    wi23[t].y = kk * i3;
    wh01[t].x = kk * w0;
    wh01[t].y = kk * w1;
    wh23[t].x = kk * w2;
    wh23[t].y = kk * w3;
    bias2[t].x = kk * bs;
    bias2[t].y = 0.0f;
  }
  v2 wo01v, wo23v, bo2;
  wo01v.x = Wout[0];
  wo01v.y = Wout[1];
  wo23v.x = Wout[2];
  wo23v.y = Wout[3];
  bo2.x = bout[0];
  bo2.y = 0.0f;

  const float2 *__restrict__ px = (const float2 *)x;

  // ---- state ----
  v2 hv01, hv23;
  hv01.x = 0.0f;
  hv01.y = 0.0f;
  hv23.x = 0.0f;
  hv23.y = 0.0f;
  float cKT = 0.0f;
  float hx0, hx1, hx2, hx3; // input vector for THIS tick
  v2 y0, y1, y2, y3, y4, y5, y6, y7;

  // initial hin (tick 0): layer-0 lanes get x(0), others 0
  {
    float2 x00 = px[bidx];
    hx0 = lz ? x00.x : 0.0f;
    hx1 = lz ? x00.y : 0.0f;
    hx2 = 0.0f;
    hx3 = 0.0f;
  }

  // prime x ring: slot U holds x(U+1) for epoch 0 (folded into TICK(U)'s
  // handoff DPP as the input of tick U+1)
  float2 xc0 = px[1 * B_SZ + bidx];
  float2 xc1 = px[2 * B_SZ + bidx];
  float2 xc2 = px[3 * B_SZ + bidx];
  float2 xc3 = px[4 * B_SZ + bidx];
  float2 xc4 = px[5 * B_SZ + bidx];
  float2 xc5 = px[6 * B_SZ + bidx];
  float2 xc6 = px[7 * B_SZ + bidx];
  float2 xc7 = px[8 * B_SZ + bidx];

  // epoch-k reload pointer (epoch k loads slot U := x(8k+9+U))
  const float2 *__restrict__ pxk = px + 9 * B_SZ + bidx;
  // epoch-k y pointer (epoch k stores t = 8k-6+U); set after epoch 0
  float *__restrict__ ypk;

  // ---- epoch 0 (peeled: warm-up resets; stores only t=0,1) ----
  TICK(0); RESET(0); XLOAD(0);
  TICK(1); RESET(1); XLOAD(1);
  TICK(2); RESET(2); XLOAD(2);
  TICK(3); RESET(3); XLOAD(3);
  TICK(4); RESET(4); XLOAD(4);
  TICK(5); RESET(5); XLOAD(5);
  TICK(6); XLOAD(6);
  TICK(7); XLOAD(7);
  if (yl) {
    out[bidx] = y6.x + y6.y;        // t = 0
    out[B_SZ + bidx] = y7.x + y7.y; // t = 1
  }
  pxk += 8 * B_SZ;
  ypk = out + 2 * B_SZ + bidx;

  // ---- main epochs k = 1..253 (all loads & stores in-bounds) ----
#pragma unroll 1
  for (int k = 1; k < 254; ++k) {
    TICK(0); XLOAD(0);
    TICK(1); XLOAD(1);
    TICK(2); XLOAD(2);
    TICK(3); XLOAD(3);
    TICK(4); XLOAD(4);
    TICK(5); XLOAD(5);
    TICK(6); XLOAD(6);
    TICK(7); XLOAD(7);
    if (yl) {
      YST(0); YST(1); YST(2); YST(3); YST(4); YST(5); YST(6); YST(7);
    }
    pxk += 8 * B_SZ;
    ypk += 8 * B_SZ;
  }

  // ---- epoch 254: last slot's reload would be x(2048) -> clamp ----
  TICK(0); XLOAD(0);
  TICK(1); XLOAD(1);
  TICK(2); XLOAD(2);
  TICK(3); XLOAD(3);
  TICK(4); XLOAD(4);
  TICK(5); XLOAD(5);
  TICK(6); XLOAD(6);
  TICK(7); XLOAD7C;
  if (yl) {
    YST(0); YST(1); YST(2); YST(3); YST(4); YST(5); YST(6); YST(7);
  }
  ypk += 8 * B_SZ;

  // ---- epoch 255: consumes last real x values; no reloads ----
  TICK(0);
  TICK(1);
  TICK(2);
  TICK(3);
  TICK(4);
  TICK(5);
  TICK(6);
  TICK(7);
  if (yl) {
    YST(0); YST(1); YST(2); YST(3); YST(4); YST(5); YST(6); YST(7);
  }
  ypk += 8 * B_SZ;

  // ---- epoch 256 (drain): 6 ticks, stores t = 2042..2047 ----
  TICK(0);
  TICK(1);
  TICK(2);
  TICK(3);
  TICK(4);
  TICK(5);
  if (yl) {
    YST(0); YST(1); YST(2); YST(3); YST(4); YST(5);
  }
}

extern "C" void kernel_launch(void *const *d_in, const int *in_sizes, int n_in,
                              void *d_out, int out_size, void *d_ws,
                              size_t ws_size, hipStream_t stream) {
  (void)in_sizes;
  (void)n_in;
  (void)out_size;
  (void)d_ws;
  (void)ws_size;
  const float *x = (const float *)d_in[0];
  const float *Wih0 = (const float *)d_in[1];
  const float *Whh0 = (const float *)d_in[2];
  const float *bih0 = (const float *)d_in[3];
  const float *bhh0 = (const float *)d_in[4];
  const float *Wihr = (const float *)d_in[5];
  const float *Whhr = (const float *)d_in[6];
  const float *bihr = (const float *)d_in[7];
  const float *bhhr = (const float *)d_in[8];
  const float *Wout = (const float *)d_in[9];
  const float *bout = (const float *)d_in[10];
  lstm_kernel<<<dim3(B_SZ), dim3(64), 0, stream>>>(
      x, Wih0, Whh0, bih0, bhh0, Wihr, Whhr, bihr, bhhr, Wout, bout,
      (float *)d_out);
}

// Round 6
// 574.663 us; speedup vs baseline: 1.0795x; 1.0795x over previous
//
#include <hip/hip_runtime.h>

#define S_LEN 2048
#define B_SZ 2048

typedef float v2 __attribute__((ext_vector_type(2)));
#define FMA2(a, b, c) __builtin_elementwise_fma((a), (b), (c))

// Pure-VALU DPP move (quad_perm patterns; old=0, bound_ctrl=1).
template <int CTRL>
__device__ __forceinline__ float dppmov(float v) {
  int r = __builtin_amdgcn_update_dpp(0, __builtin_bit_cast(int, v), CTRL, 0xF,
                                      0xF, true);
  return __builtin_bit_cast(float, r);
}

// DPP with explicit old operand: invalid lanes (bound_ctrl=0) keep `old`.
// row_shr:4 invalid lanes are exactly the l==0 lanes -> x rides in `old`.
template <int CTRL, bool BC>
__device__ __forceinline__ float dppold(float old, float v) {
  int r = __builtin_amdgcn_update_dpp(__builtin_bit_cast(int, old),
                                      __builtin_bit_cast(int, v), CTRL, 0xF,
                                      0xF, BC);
  return __builtin_bit_cast(float, r);
}

// R15: two INDEPENDENT recurrence streams per wave (ILP, not occupancy).
// R10-R13: wall/tick = issue(~112cy) + unhidden chain(~210cy), additive
// for a lone in-order wave. R14 (co-resident duplicate waves) gave ZERO
// stall-filling (605us = 2x313): identical waves phase-lock. Fix: the
// stall-filler must be independent work INSIDE the wave. Each block owns
// 8 batches: stream A = batches blk*8+b (b=0..3 by lane row), stream B =
// blk*8+4+b. Separate register state, statement-interleaved in TICK2 so
// chain B's FMAs issue during chain A's exp/rcp stalls. Issue/tick-pair
// ~224cy >= chain 210cy -> chain hidden. Grid = 256 blocks (1 wave/CU;
// makespan = per-wave latency). Per-stream arithmetic bit-identical to
// R14 (passed, absmax 0.001953125). Lane = b*16 + l*4 + j unchanged;
// weights shared across streams (same l,j roles).
#define TICK2(U)                                                               \
  {                                                                            \
    v2 h01A, h23A, h01B, h23B;                                                 \
    h01A.x = hx0_A;                                                            \
    h01B.x = hx0_B;                                                            \
    h01A.y = hx1_A;                                                            \
    h01B.y = hx1_B;                                                            \
    h23A.x = hx2_A;                                                            \
    h23B.x = hx2_B;                                                            \
    h23A.y = hx3_A;                                                            \
    h23B.y = hx3_B;                                                            \
    v2 A0 = FMA2(wi01[0], h01A, bias2[0]);                                     \
    v2 B0 = FMA2(wi01[0], h01B, bias2[0]);                                     \
    v2 A1 = FMA2(wi01[1], h01A, bias2[1]);                                     \
    v2 B1 = FMA2(wi01[1], h01B, bias2[1]);                                     \
    v2 A2 = FMA2(wi01[2], h01A, bias2[2]);                                     \
    v2 B2 = FMA2(wi01[2], h01B, bias2[2]);                                     \
    v2 A3 = FMA2(wi01[3], h01A, bias2[3]);                                     \
    v2 B3 = FMA2(wi01[3], h01B, bias2[3]);                                     \
    A0 = FMA2(wi23[0], h23A, A0);                                              \
    B0 = FMA2(wi23[0], h23B, B0);                                              \
    A1 = FMA2(wi23[1], h23A, A1);                                              \
    B1 = FMA2(wi23[1], h23B, B1);                                              \
    A2 = FMA2(wi23[2], h23A, A2);                                              \
    B2 = FMA2(wi23[2], h23B, B2);                                              \
    A3 = FMA2(wi23[3], h23A, A3);                                              \
    B3 = FMA2(wi23[3], h23B, B3);                                              \
    A0 = FMA2(wh01[0], hv01_A, A0);                                            \
    B0 = FMA2(wh01[0], hv01_B, B0);                                            \
    A1 = FMA2(wh01[1], hv01_A, A1);                                            \
    B1 = FMA2(wh01[1], hv01_B, B1);                                            \
    A2 = FMA2(wh01[2], hv01_A, A2);                                            \
    B2 = FMA2(wh01[2], hv01_B, B2);                                            \
    A3 = FMA2(wh01[3], hv01_A, A3);                                            \
    B3 = FMA2(wh01[3], hv01_B, B3);                                            \
    A0 = FMA2(wh23[0], hv23_A, A0);                                            \
    B0 = FMA2(wh23[0], hv23_B, B0);                                            \
    A1 = FMA2(wh23[1], hv23_A, A1);                                            \
    B1 = FMA2(wh23[1], hv23_B, B1);                                            \
    A2 = FMA2(wh23[2], hv23_A, A2);                                            \
    B2 = FMA2(wh23[2], hv23_B, B2);                                            \
    A3 = FMA2(wh23[3], hv23_A, A3);                                            \
    B3 = FMA2(wh23[3], hv23_B, B3);                                            \
    float a0A = A0.x + A0.y, a0B = B0.x + B0.y;                                \
    float a1A = A1.x + A1.y, a1B = B1.x + B1.y;                                \
    float a2A = A2.x + A2.y, a2B = B2.x + B2.y;                                \
    float a3A = A3.x + A3.y, a3B = B3.x + B3.y;                                \
    float e0A = __builtin_amdgcn_exp2f(a0A);                                   \
    float e0B = __builtin_amdgcn_exp2f(a0B);                                   \
    float e1A = __builtin_amdgcn_exp2f(a1A);                                   \
    float e1B = __builtin_amdgcn_exp2f(a1B);                                   \
    float e2A = __builtin_amdgcn_exp2f(a2A);                                   \
    float e2B = __builtin_amdgcn_exp2f(a2B);                                   \
    float e3A = __builtin_amdgcn_exp2f(a3A);                                   \
    float e3B = __builtin_amdgcn_exp2f(a3B);                                   \
    float r0A = __builtin_amdgcn_rcpf(1.0f + e0A); /* sigmoid(i) */            \
    float r0B = __builtin_amdgcn_rcpf(1.0f + e0B);                             \
    float r1A = __builtin_amdgcn_rcpf(1.0f + e1A); /* sigmoid(f) */            \
    float r1B = __builtin_amdgcn_rcpf(1.0f + e1B);                             \
    float r2A = __builtin_amdgcn_rcpf(1.0f + e2A); /* (tanh(g)+1)/2 */         \
    float r2B = __builtin_amdgcn_rcpf(1.0f + e2B);                             \
    float r3A = __builtin_amdgcn_rcpf(1.0f + e3A); /* sigmoid(o) */            \
    float r3B = __builtin_amdgcn_rcpf(1.0f + e3B);                             \
    float giA = KT * r0A, giB = KT * r0B; /* KT fold: cKT = KT*c */            \
    float ggA = fmaf(2.0f, r2A, -1.0f);   /* tanh(g) */                        \
    float ggB = fmaf(2.0f, r2B, -1.0f);                                        \
    cKT_A = fmaf(r1A, cKT_A, giA * ggA);                                       \
    cKT_B = fmaf(r1B, cKT_B, giB * ggB);                                       \
    float teA = __builtin_amdgcn_exp2f(cKT_A);                                 \
    float teB = __builtin_amdgcn_exp2f(cKT_B);                                 \
    float trA = __builtin_amdgcn_rcpf(1.0f + teA);                             \
    float trB = __builtin_amdgcn_rcpf(1.0f + teB);                             \
    float go2A = r3A + r3A, go2B = r3B + r3B;                                  \
    float hhA = fmaf(go2A, trA, -r3A); /* = o * tanh(c) */                     \
    float hhB = fmaf(go2B, trB, -r3B);                                         \
    /* next-tick input from OLD hv (pre-update); l0 lanes keep xc (old) */     \
    hx0_A = dppold<0x114, false>(xc##U##_A.x, hv01_A.x); /* row_shr:4 */       \
    hx0_B = dppold<0x114, false>(xc##U##_B.x, hv01_B.x);                       \
    hx1_A = dppold<0x114, false>(xc##U##_A.y, hv01_A.y);                       \
    hx1_B = dppold<0x114, false>(xc##U##_B.y, hv01_B.y);                       \
    hx2_A = dppold<0x114, true>(0.0f, hv23_A.x);                               \
    hx2_B = dppold<0x114, true>(0.0f, hv23_B.x);                               \
    hx3_A = dppold<0x114, true>(0.0f, hv23_A.y);                               \
    hx3_B = dppold<0x114, true>(0.0f, hv23_B.y);                               \
    hv01_A.x = hhA;                                                            \
    hv01_B.x = hhB;                                                            \
    hv01_A.y = dppmov<0x39>(hhA); /* h_{(j+1)&3} */                            \
    hv01_B.y = dppmov<0x39>(hhB);                                              \
    hv23_A.x = dppmov<0x4E>(hhA); /* h_{(j+2)&3} */                            \
    hv23_B.x = dppmov<0x4E>(hhB);                                              \
    hv23_A.y = dppmov<0x93>(hhA); /* h_{(j+3)&3} */                            \
    hv23_B.y = dppmov<0x93>(hhB);                                              \
    /* y slot: partial dot (horizontal add deferred to epoch store) */         \
    y##U##_A = FMA2(wo01v, hv01_A, bo2);                                       \
    y##U##_B = FMA2(wo01v, hv01_B, bo2);                                       \
    y##U##_A = FMA2(wo23v, hv23_A, y##U##_A);                                  \
    y##U##_B = FMA2(wo23v, hv23_B, y##U##_B);                                  \
  }

// warm-up reset: layer l is live from tau = 2l (both streams)
#define RESET2(U)                                                              \
  if (2 * l > (U)) {                                                           \
    cKT_A = 0.0f;                                                              \
    cKT_B = 0.0f;                                                              \
    hv01_A.x = 0.0f;                                                           \
    hv01_A.y = 0.0f;                                                           \
    hv23_A.x = 0.0f;                                                           \
    hv23_A.y = 0.0f;                                                           \
    hv01_B.x = 0.0f;                                                           \
    hv01_B.y = 0.0f;                                                           \
    hv23_B.x = 0.0f;                                                           \
    hv23_B.y = 0.0f;                                                           \
  }

// reload slot U (just consumed) with its value for the NEXT epoch:
// epoch k's pointer pxk = px + (8k+9)*B_SZ + bidxA; stream B = +4 floats2
#define XLOAD2(U)                                                              \
  xc##U##_A = pxk[(U)*B_SZ];                                                   \
  xc##U##_B = pxk[(U)*B_SZ + 4];
#define XLOAD7C2                                                               \
  xc7_A = pxk[6 * B_SZ]; /* tail clamp: x(2047) dup */                         \
  xc7_B = pxk[6 * B_SZ + 4];

#define YST2(U)                                                                \
  ypk[(U)*B_SZ] = y##U##_A.x + y##U##_A.y;                                     \
  ypk[(U)*B_SZ + 4] = y##U##_B.x + y##U##_B.y;

__global__ void __launch_bounds__(64, 1)
    lstm_kernel(const float *__restrict__ x, const float *__restrict__ Wih0,
                const float *__restrict__ Whh0, const float *__restrict__ bih0,
                const float *__restrict__ bhh0, const float *__restrict__ Wihr,
                const float *__restrict__ Whhr, const float *__restrict__ bihr,
                const float *__restrict__ bhhr, const float *__restrict__ Wout,
                const float *__restrict__ bout, float *__restrict__ out) {
  const int lane = threadIdx.x & 63;
  const int b = lane >> 4;       // batch slot (within each stream)
  const int l = (lane >> 2) & 3; // layer
  const int j = lane & 3;        // hidden unit
  const int bidxA = blockIdx.x * 8 + b; // stream A batch; B = +4
  const bool lz = (l == 0);
  const bool yl = (l == 3) && (j == 0);

  const float L2E = 1.4426950408889634f;
  const float KT = -2.8853900817779268f; // -2*log2(e)
  const float kks[4] = {-L2E, -L2E, -2.0f * L2E, -L2E};

  // ---- per-lane weights: all 4 gates of hidden j, layer l; pk-paired,
  //      pre-scaled by kk_t; wh AND (l>0) wi pre-rotated by j to match
  //      the rotated h convention of the row_shr:4 handoff. Shared by
  //      both streams (same lane roles). ----
  v2 wi01[4], wi23[4], wh01[4], wh23[4], bias2[4];
#pragma unroll
  for (int t = 0; t < 4; ++t) {
    const int row = t * 4 + j;
    const float kk = kks[t];
    float i0, i1, i2, i3, w0, w1, w2, w3, bs;
    if (l == 0) {
      i0 = Wih0[row * 2 + 0];
      i1 = Wih0[row * 2 + 1];
      i2 = 0.0f;
      i3 = 0.0f;
      w0 = Whh0[row * 4 + j];
      w1 = Whh0[row * 4 + ((j + 1) & 3)];
      w2 = Whh0[row * 4 + ((j + 2) & 3)];
      w3 = Whh0[row * 4 + ((j + 3) & 3)];
      bs = bih0[row] + bhh0[row];
    } else {
      const int m = l - 1;
      i0 = Wihr[m * 64 + row * 4 + j];
      i1 = Wihr[m * 64 + row * 4 + ((j + 1) & 3)];
      i2 = Wihr[m * 64 + row * 4 + ((j + 2) & 3)];
      i3 = Wihr[m * 64 + row * 4 + ((j + 3) & 3)];
      w0 = Whhr[m * 64 + row * 4 + j];
      w1 = Whhr[m * 64 + row * 4 + ((j + 1) & 3)];
      w2 = Whhr[m * 64 + row * 4 + ((j + 2) & 3)];
      w3 = Whhr[m * 64 + row * 4 + ((j + 3) & 3)];
      bs = bihr[m * 16 + row] + bhhr[m * 16 + row];
    }
    wi01[t].x = kk * i0;
    wi01[t].y = kk * i1;
    wi23[t].x = kk * i2;
    wi23[t].y = kk * i3;
    wh01[t].x = kk * w0;
    wh01[t].y = kk * w1;
    wh23[t].x = kk * w2;
    wh23[t].y = kk * w3;
    bias2[t].x = kk * bs;
    bias2[t].y = 0.0f;
  }
  v2 wo01v, wo23v, bo2;
  wo01v.x = Wout[0];
  wo01v.y = Wout[1];
  wo23v.x = Wout[2];
  wo23v.y = Wout[3];
  bo2.x = bout[0];
  bo2.y = 0.0f;

  const float2 *__restrict__ px = (const float2 *)x;

  // ---- state (x2 streams) ----
  v2 hv01_A, hv23_A, hv01_B, hv23_B;
  hv01_A.x = 0.0f; hv01_A.y = 0.0f; hv23_A.x = 0.0f; hv23_A.y = 0.0f;
  hv01_B.x = 0.0f; hv01_B.y = 0.0f; hv23_B.x = 0.0f; hv23_B.y = 0.0f;
  float cKT_A = 0.0f, cKT_B = 0.0f;
  float hx0_A, hx1_A, hx2_A, hx3_A;
  float hx0_B, hx1_B, hx2_B, hx3_B;
  v2 y0_A, y1_A, y2_A, y3_A, y4_A, y5_A, y6_A, y7_A;
  v2 y0_B, y1_B, y2_B, y3_B, y4_B, y5_B, y6_B, y7_B;

  // initial hin (tick 0): layer-0 lanes get x(0), others 0
  {
    float2 xA = px[bidxA];
    float2 xB = px[bidxA + 4];
    hx0_A = lz ? xA.x : 0.0f;
    hx1_A = lz ? xA.y : 0.0f;
    hx0_B = lz ? xB.x : 0.0f;
    hx1_B = lz ? xB.y : 0.0f;
    hx2_A = 0.0f;
    hx3_A = 0.0f;
    hx2_B = 0.0f;
    hx3_B = 0.0f;
  }

  // prime x ring: slot U holds x(U+1) for epoch 0
  float2 xc0_A = px[1 * B_SZ + bidxA], xc0_B = px[1 * B_SZ + bidxA + 4];
  float2 xc1_A = px[2 * B_SZ + bidxA], xc1_B = px[2 * B_SZ + bidxA + 4];
  float2 xc2_A = px[3 * B_SZ + bidxA], xc2_B = px[3 * B_SZ + bidxA + 4];
  float2 xc3_A = px[4 * B_SZ + bidxA], xc3_B = px[4 * B_SZ + bidxA + 4];
  float2 xc4_A = px[5 * B_SZ + bidxA], xc4_B = px[5 * B_SZ + bidxA + 4];
  float2 xc5_A = px[6 * B_SZ + bidxA], xc5_B = px[6 * B_SZ + bidxA + 4];
  float2 xc6_A = px[7 * B_SZ + bidxA], xc6_B = px[7 * B_SZ + bidxA + 4];
  float2 xc7_A = px[8 * B_SZ + bidxA], xc7_B = px[8 * B_SZ + bidxA + 4];

  // epoch-k reload pointer (epoch k loads slot U := x(8k+9+U))
  const float2 *__restrict__ pxk = px + 9 * B_SZ + bidxA;
  // epoch-k y pointer (epoch k stores t = 8k-6+U); set after epoch 0
  float *__restrict__ ypk;

  // ---- epoch 0 (peeled: warm-up resets; stores only t=0,1) ----
  TICK2(0); RESET2(0); XLOAD2(0);
  TICK2(1); RESET2(1); XLOAD2(1);
  TICK2(2); RESET2(2); XLOAD2(2);
  TICK2(3); RESET2(3); XLOAD2(3);
  TICK2(4); RESET2(4); XLOAD2(4);
  TICK2(5); RESET2(5); XLOAD2(5);
  TICK2(6); XLOAD2(6);
  TICK2(7); XLOAD2(7);
  if (yl) {
    out[bidxA] = y6_A.x + y6_A.y;              // t = 0, stream A
    out[bidxA + 4] = y6_B.x + y6_B.y;          // t = 0, stream B
    out[B_SZ + bidxA] = y7_A.x + y7_A.y;       // t = 1, stream A
    out[B_SZ + bidxA + 4] = y7_B.x + y7_B.y;   // t = 1, stream B
  }
  pxk += 8 * B_SZ;
  ypk = out + 2 * B_SZ + bidxA;

  // ---- main epochs k = 1..253 (all loads & stores in-bounds) ----
#pragma unroll 1
  for (int k = 1; k < 254; ++k) {
    TICK2(0); XLOAD2(0);
    TICK2(1); XLOAD2(1);
    TICK2(2); XLOAD2(2);
    TICK2(3); XLOAD2(3);
    TICK2(4); XLOAD2(4);
    TICK2(5); XLOAD2(5);
    TICK2(6); XLOAD2(6);
    TICK2(7); XLOAD2(7);
    if (yl) {
      YST2(0); YST2(1); YST2(2); YST2(3);
      YST2(4); YST2(5); YST2(6); YST2(7);
    }
    pxk += 8 * B_SZ;
    ypk += 8 * B_SZ;
  }

  // ---- epoch 254: last slot's reload would be x(2048) -> clamp ----
  TICK2(0); XLOAD2(0);
  TICK2(1); XLOAD2(1);
  TICK2(2); XLOAD2(2);
  TICK2(3); XLOAD2(3);
  TICK2(4); XLOAD2(4);
  TICK2(5); XLOAD2(5);
  TICK2(6); XLOAD2(6);
  TICK2(7); XLOAD7C2;
  if (yl) {
    YST2(0); YST2(1); YST2(2); YST2(3);
    YST2(4); YST2(5); YST2(6); YST2(7);
  }
  ypk += 8 * B_SZ;

  // ---- epoch 255: consumes last real x values; no reloads ----
  TICK2(0);
  TICK2(1);
  TICK2(2);
  TICK2(3);
  TICK2(4);
  TICK2(5);
  TICK2(6);
  TICK2(7);
  if (yl) {
    YST2(0); YST2(1); YST2(2); YST2(3);
    YST2(4); YST2(5); YST2(6); YST2(7);
  }
  ypk += 8 * B_SZ;

  // ---- epoch 256 (drain): 6 ticks, stores t = 2042..2047 ----
  TICK2(0);
  TICK2(1);
  TICK2(2);
  TICK2(3);
  TICK2(4);
  TICK2(5);
  if (yl) {
    YST2(0); YST2(1); YST2(2); YST2(3); YST2(4); YST2(5);
  }
}

extern "C" void kernel_launch(void *const *d_in, const int *in_sizes, int n_in,
                              void *d_out, int out_size, void *d_ws,
                              size_t ws_size, hipStream_t stream) {
  (void)in_sizes;
  (void)n_in;
  (void)out_size;
  (void)d_ws;
  (void)ws_size;
  const float *x = (const float *)d_in[0];
  const float *Wih0 = (const float *)d_in[1];
  const float *Whh0 = (const float *)d_in[2];
  const float *bih0 = (const float *)d_in[3];
  const float *bhh0 = (const float *)d_in[4];
  const float *Wihr = (const float *)d_in[5];
  const float *Whhr = (const float *)d_in[6];
  const float *bihr = (const float *)d_in[7];
  const float *bhhr = (const float *)d_in[8];
  const float *Wout = (const float *)d_in[9];
  const float *bout = (const float *)d_in[10];
  lstm_kernel<<<dim3(B_SZ / 8), dim3(64), 0, stream>>>(
      x, Wih0, Whh0, bih0, bhh0, Wihr, Whhr, bihr, bhhr, Wout, bout,
      (float *)d_out);
}

// Round 7
// 382.262 us; speedup vs baseline: 1.6228x; 1.5033x over previous
//
#include <hip/hip_runtime.h>

#define S_LEN 2048
#define B_SZ 2048

typedef float v2 __attribute__((ext_vector_type(2)));
#define FMA2(a, b, c) __builtin_elementwise_fma((a), (b), (c))

// Pure-VALU DPP move (quad_perm patterns; old=0, bound_ctrl=1).
template <int CTRL>
__device__ __forceinline__ float dppmov(float v) {
  int r = __builtin_amdgcn_update_dpp(0, __builtin_bit_cast(int, v), CTRL, 0xF,
                                      0xF, true);
  return __builtin_bit_cast(float, r);
}

// DPP with explicit old operand: invalid lanes (bound_ctrl=0) keep `old`.
// row_shr:4 invalid lanes are exactly the l==0 lanes -> x rides in `old`.
template <int CTRL, bool BC>
__device__ __forceinline__ float dppold(float old, float v) {
  int r = __builtin_amdgcn_update_dpp(__builtin_bit_cast(int, old),
                                      __builtin_bit_cast(int, v), CTRL, 0xF,
                                      0xF, BC);
  return __builtin_bit_cast(float, r);
}

// lane^16 exchange (BitMode swizzle: xor_mask=16 -> offset 0x401F).
__device__ __forceinline__ float swz16(float v) {
  int r = __builtin_amdgcn_ds_swizzle(__builtin_bit_cast(int, v), 0x401F);
  return __builtin_bit_cast(float, r);
}

// R16: gate-pair split. R15's counters closed the model: the kernel is
// VALU-ISSUE-bound (per-active-SIMD VALUBusy 85%; v_pk_fma_f32 = 4cy,
// v_exp/v_rcp = 8cy wave64), and 512 of 1024 SIMDs are idle. Halve the
// per-wave instruction stream and double the wave count:
// lane = b*32 + p*16 + l*4 + j  (2 batches/wave, gate-pair p per row:
// p=0 computes gates i,f; p=1 computes g,o). Each 16-lane row keeps the
// R12 structure exactly (quads=layers, quad_perm rotations, row_shr:4
// layer handoff, x in DPP old operand). Gate-pair exchange = 2
// ds_swizzle XOR-16 + 4 cndmask; cell computed redundantly by both rows
// (uniform). Per-gate arithmetic sequence identical to R12 ->
// bit-identical output. Grid = 1024 blocks = 1 wave/SIMD chip-wide.
// Per-tick issue ~136cy vs R12's 265.
#define TICK(U)                                                                \
  {                                                                            \
    v2 h01, h23;                                                               \
    h01.x = hx0;                                                               \
    h01.y = hx1;                                                               \
    h23.x = hx2;                                                               \
    h23.y = hx3;                                                               \
    v2 A0 = FMA2(wi01[0], h01, bias2[0]);                                      \
    v2 A1 = FMA2(wi01[1], h01, bias2[1]);                                      \
    A0 = FMA2(wi23[0], h23, A0);                                               \
    A1 = FMA2(wi23[1], h23, A1);                                               \
    A0 = FMA2(wh01[0], hv01, A0);                                              \
    A1 = FMA2(wh01[1], hv01, A1);                                              \
    A0 = FMA2(wh23[0], hv23, A0);                                              \
    A1 = FMA2(wh23[1], hv23, A1);                                              \
    float a0 = A0.x + A0.y, a1 = A1.x + A1.y;                                  \
    float e0 = __builtin_amdgcn_exp2f(a0); /* gates pre-scaled by kk_t */      \
    float e1 = __builtin_amdgcn_exp2f(a1);                                     \
    float r0 = __builtin_amdgcn_rcpf(1.0f + e0);                               \
    float r1 = __builtin_amdgcn_rcpf(1.0f + e1);                               \
    /* p0 row now holds {sig(i), sig(f)}, p1 row {(th(g)+1)/2, sig(o)} */      \
    float s0 = swz16(r0); /* partner row's r0 */                               \
    float s1 = swz16(r1); /* partner row's r1 */                               \
    float ii = pp ? s0 : r0;                                                   \
    float ff = pp ? s1 : r1;                                                   \
    float tg = pp ? r0 : s0;                                                   \
    float oo = pp ? r1 : s1;                                                   \
    float gi = KT * ii;               /* KT fold: cKT = KT*c */                \
    float gg = fmaf(2.0f, tg, -1.0f); /* tanh(g) */                            \
    cKT = fmaf(ff, cKT, gi * gg);                                              \
    float te = __builtin_amdgcn_exp2f(cKT);                                    \
    float tr = __builtin_amdgcn_rcpf(1.0f + te);                               \
    float go2 = oo + oo;                                                       \
    float hh = fmaf(go2, tr, -oo); /* = o * tanh(c) */                         \
    /* next-tick input from OLD hv (pre-update); l0 lanes keep xc (old) */     \
    hx0 = dppold<0x114, false>(xc##U.x, hv01.x); /* row_shr:4 */               \
    hx1 = dppold<0x114, false>(xc##U.y, hv01.y);                               \
    hx2 = dppold<0x114, true>(0.0f, hv23.x);                                   \
    hx3 = dppold<0x114, true>(0.0f, hv23.y);                                   \
    hv01.x = hh;                                                               \
    hv01.y = dppmov<0x39>(hh); /* h_{(j+1)&3} */                               \
    hv23.x = dppmov<0x4E>(hh); /* h_{(j+2)&3} */                               \
    hv23.y = dppmov<0x93>(hh); /* h_{(j+3)&3} */                               \
    /* y slot: partial dot (horizontal add deferred to epoch store) */         \
    y##U = FMA2(wo01v, hv01, bo2);                                             \
    y##U = FMA2(wo23v, hv23, y##U);                                            \
  }

// warm-up reset: layer l is live from tau = 2l
#define RESET(U)                                                               \
  if (2 * l > (U)) {                                                           \
    cKT = 0.0f;                                                                \
    hv01.x = 0.0f;                                                             \
    hv01.y = 0.0f;                                                             \
    hv23.x = 0.0f;                                                             \
    hv23.y = 0.0f;                                                             \
  }

// reload slot U (just consumed) with its value for the NEXT epoch:
// epoch k's pointer pxk = px + (8k+9)*B_SZ + bidx -> slot U := x(8k+9+U)
#define XLOAD(U) xc##U = pxk[(U)*B_SZ];
#define XLOAD7C xc7 = pxk[6 * B_SZ]; /* tail clamp: x(2047) dup */

#define YST(U) ypk[(U)*B_SZ] = y##U.x + y##U.y;

__global__ void __launch_bounds__(64, 1)
    lstm_kernel(const float *__restrict__ x, const float *__restrict__ Wih0,
                const float *__restrict__ Whh0, const float *__restrict__ bih0,
                const float *__restrict__ bhh0, const float *__restrict__ Wihr,
                const float *__restrict__ Whhr, const float *__restrict__ bihr,
                const float *__restrict__ bhhr, const float *__restrict__ Wout,
                const float *__restrict__ bout, float *__restrict__ out) {
  const int lane = threadIdx.x & 63;
  const int b = lane >> 5;       // batch slot (2 per wave)
  const int p = (lane >> 4) & 1; // gate pair: 0 -> {i,f}, 1 -> {g,o}
  const int l = (lane >> 2) & 3; // layer
  const int j = lane & 3;        // hidden unit
  const int bidx = blockIdx.x * 2 + b;
  const bool pp = (p == 1);
  const bool lz = (l == 0);
  const bool yl = (p == 0) && (l == 3) && (j == 0);

  const float L2E = 1.4426950408889634f;
  const float KT = -2.8853900817779268f; // -2*log2(e)
  const float kks[4] = {-L2E, -L2E, -2.0f * L2E, -L2E};

  // ---- per-lane weights: 2 gates (t = 2p+n, n=0,1) of hidden j, layer
  //      l; pk-paired, pre-scaled by kk_t; wh AND (l>0) wi pre-rotated
  //      by j to match the rotated h convention of the row_shr:4
  //      handoff. Same per-gate load/scale sequence as R12. ----
  v2 wi01[2], wi23[2], wh01[2], wh23[2], bias2[2];
#pragma unroll
  for (int n = 0; n < 2; ++n) {
    const int t = 2 * p + n;
    const int row = t * 4 + j;
    const float kk = kks[t];
    float i0, i1, i2, i3, w0, w1, w2, w3, bs;
    if (l == 0) {
      i0 = Wih0[row * 2 + 0];
      i1 = Wih0[row * 2 + 1];
      i2 = 0.0f;
      i3 = 0.0f;
      w0 = Whh0[row * 4 + j];
      w1 = Whh0[row * 4 + ((j + 1) & 3)];
      w2 = Whh0[row * 4 + ((j + 2) & 3)];
      w3 = Whh0[row * 4 + ((j + 3) & 3)];
      bs = bih0[row] + bhh0[row];
    } else {
      const int m = l - 1;
      i0 = Wihr[m * 64 + row * 4 + j];
      i1 = Wihr[m * 64 + row * 4 + ((j + 1) & 3)];
      i2 = Wihr[m * 64 + row * 4 + ((j + 2) & 3)];
      i3 = Wihr[m * 64 + row * 4 + ((j + 3) & 3)];
      w0 = Whhr[m * 64 + row * 4 + j];
      w1 = Whhr[m * 64 + row * 4 + ((j + 1) & 3)];
      w2 = Whhr[m * 64 + row * 4 + ((j + 2) & 3)];
      w3 = Whhr[m * 64 + row * 4 + ((j + 3) & 3)];
      bs = bihr[m * 16 + row] + bhhr[m * 16 + row];
    }
    wi01[n].x = kk * i0;
    wi01[n].y = kk * i1;
    wi23[n].x = kk * i2;
    wi23[n].y = kk * i3;
    wh01[n].x = kk * w0;
    wh01[n].y = kk * w1;
    wh23[n].x = kk * w2;
    wh23[n].y = kk * w3;
    bias2[n].x = kk * bs;
    bias2[n].y = 0.0f;
  }
  v2 wo01v, wo23v, bo2;
  wo01v.x = Wout[0];
  wo01v.y = Wout[1];
  wo23v.x = Wout[2];
  wo23v.y = Wout[3];
  bo2.x = bout[0];
  bo2.y = 0.0f;

  const float2 *__restrict__ px = (const float2 *)x;

  // ---- state ----
  v2 hv01, hv23;
  hv01.x = 0.0f;
  hv01.y = 0.0f;
  hv23.x = 0.0f;
  hv23.y = 0.0f;
  float cKT = 0.0f;
  float hx0, hx1, hx2, hx3; // input vector for THIS tick
  v2 y0, y1, y2, y3, y4, y5, y6, y7;

  // initial hin (tick 0): layer-0 lanes get x(0), others 0
  {
    float2 x00 = px[bidx];
    hx0 = lz ? x00.x : 0.0f;
    hx1 = lz ? x00.y : 0.0f;
    hx2 = 0.0f;
    hx3 = 0.0f;
  }

  // prime x ring: slot U holds x(U+1) for epoch 0 (folded into TICK(U)'s
  // handoff DPP as the input of tick U+1)
  float2 xc0 = px[1 * B_SZ + bidx];
  float2 xc1 = px[2 * B_SZ + bidx];
  float2 xc2 = px[3 * B_SZ + bidx];
  float2 xc3 = px[4 * B_SZ + bidx];
  float2 xc4 = px[5 * B_SZ + bidx];
  float2 xc5 = px[6 * B_SZ + bidx];
  float2 xc6 = px[7 * B_SZ + bidx];
  float2 xc7 = px[8 * B_SZ + bidx];

  // epoch-k reload pointer (epoch k loads slot U := x(8k+9+U))
  const float2 *__restrict__ pxk = px + 9 * B_SZ + bidx;
  // epoch-k y pointer (epoch k stores t = 8k-6+U); set after epoch 0
  float *__restrict__ ypk;

  // ---- epoch 0 (peeled: warm-up resets; stores only t=0,1) ----
  TICK(0); RESET(0); XLOAD(0);
  TICK(1); RESET(1); XLOAD(1);
  TICK(2); RESET(2); XLOAD(2);
  TICK(3); RESET(3); XLOAD(3);
  TICK(4); RESET(4); XLOAD(4);
  TICK(5); RESET(5); XLOAD(5);
  TICK(6); XLOAD(6);
  TICK(7); XLOAD(7);
  if (yl) {
    out[bidx] = y6.x + y6.y;        // t = 0
    out[B_SZ + bidx] = y7.x + y7.y; // t = 1
  }
  pxk += 8 * B_SZ;
  ypk = out + 2 * B_SZ + bidx;

  // ---- main epochs k = 1..253 (all loads & stores in-bounds) ----
#pragma unroll 1
  for (int k = 1; k < 254; ++k) {
    TICK(0); XLOAD(0);
    TICK(1); XLOAD(1);
    TICK(2); XLOAD(2);
    TICK(3); XLOAD(3);
    TICK(4); XLOAD(4);
    TICK(5); XLOAD(5);
    TICK(6); XLOAD(6);
    TICK(7); XLOAD(7);
    if (yl) {
      YST(0); YST(1); YST(2); YST(3); YST(4); YST(5); YST(6); YST(7);
    }
    pxk += 8 * B_SZ;
    ypk += 8 * B_SZ;
  }

  // ---- epoch 254: last slot's reload would be x(2048) -> clamp ----
  TICK(0); XLOAD(0);
  TICK(1); XLOAD(1);
  TICK(2); XLOAD(2);
  TICK(3); XLOAD(3);
  TICK(4); XLOAD(4);
  TICK(5); XLOAD(5);
  TICK(6); XLOAD(6);
  TICK(7); XLOAD7C;
  if (yl) {
    YST(0); YST(1); YST(2); YST(3); YST(4); YST(5); YST(6); YST(7);
  }
  ypk += 8 * B_SZ;

  // ---- epoch 255: consumes last real x values; no reloads ----
  TICK(0);
  TICK(1);
  TICK(2);
  TICK(3);
  TICK(4);
  TICK(5);
  TICK(6);
  TICK(7);
  if (yl) {
    YST(0); YST(1); YST(2); YST(3); YST(4); YST(5); YST(6); YST(7);
  }
  ypk += 8 * B_SZ;

  // ---- epoch 256 (drain): 6 ticks, stores t = 2042..2047 ----
  TICK(0);
  TICK(1);
  TICK(2);
  TICK(3);
  TICK(4);
  TICK(5);
  if (yl) {
    YST(0); YST(1); YST(2); YST(3); YST(4); YST(5);
  }
}

extern "C" void kernel_launch(void *const *d_in, const int *in_sizes, int n_in,
                              void *d_out, int out_size, void *d_ws,
                              size_t ws_size, hipStream_t stream) {
  (void)in_sizes;
  (void)n_in;
  (void)out_size;
  (void)d_ws;
  (void)ws_size;
  const float *x = (const float *)d_in[0];
  const float *Wih0 = (const float *)d_in[1];
  const float *Whh0 = (const float *)d_in[2];
  const float *bih0 = (const float *)d_in[3];
  const float *bhh0 = (const float *)d_in[4];
  const float *Wihr = (const float *)d_in[5];
  const float *Whhr = (const float *)d_in[6];
  const float *bihr = (const float *)d_in[7];
  const float *bhhr = (const float *)d_in[8];
  const float *Wout = (const float *)d_in[9];
  const float *bout = (const float *)d_in[10];
  lstm_kernel<<<dim3(B_SZ / 2), dim3(64), 0, stream>>>(
      x, Wih0, Whh0, bih0, bhh0, Wihr, Whhr, bihr, bhhr, Wout, bout,
      (float *)d_out);
}